// Round 1
// baseline (174.529 us; speedup 1.0000x reference)
//
#include <hip/hip_runtime.h>
#include <hip/hip_cooperative_groups.h>

namespace cg = cooperative_groups;

// Problem constants (B, N1, N2, D) = (256, 32, 32, 512)
#define BB 256
#define NN 32
#define DD 512
#define D2 (DD / 2)  // float2 / packed-dword columns per row

static __device__ inline unsigned f2bf(float x) {
  union { float f; unsigned u; } a; a.f = x;
  unsigned r = a.u + 0x7fff + ((a.u >> 16) & 1);  // round-to-nearest-even
  return r >> 16;
}

// One cooperative dispatch, 256 blocks x 512 threads (8 waves/block, 1 block/CU
// guaranteed co-resident -> grid.sync() is safe).
//
// Phase 1 (all 131072 threads, one float2 column each):
//   u[b][d]   = sum_n ner[b][n][d]          (fp32, 512 KB)
//   vTp[d2][c] = bf16x2(sum_f face[c][f][2*d2], ...[2*d2+1])  (256 KB, transposed)
// Phase 2 (block b = logits row b):
//   lg[c] = <u[b], v[c]> / 1024 ; LSE over c ; atomicAdd of -(lg[b]-lse)/256.
__global__ __launch_bounds__(512) void fused_nce(
    const float* __restrict__ ner, const float* __restrict__ face,
    float* __restrict__ u, unsigned* __restrict__ vTp,
    float* __restrict__ out) {
  const int t = threadIdx.x;
  const int idx = blockIdx.x * 512 + t;

  // Re-zero out every launch/replay (harness poisons 0xAA); all atomicAdds
  // happen after grid.sync(), so this is race-free.
  if (idx == 0) atomicExch(out, 0.0f);

  {  // ---- Phase 1: row-sum reductions, 8 B/lane coalesced loads ----
    const bool is_ner = idx < (BB * D2);
    const int j = is_ner ? idx : idx - BB * D2;
    const int row = j >> 8;   // D2 = 256 float2 per row
    const int d2 = j & 255;
    const float2* p =
        (const float2*)(is_ner ? ner : face) + (size_t)row * (NN * D2) + d2;
    float sx = 0.f, sy = 0.f;
#pragma unroll
    for (int n = 0; n < NN; ++n) {
      float2 x = p[(size_t)n * D2];
      sx += x.x; sy += x.y;
    }
    if (is_ner) {
      ((float2*)u)[(size_t)row * D2 + d2] = make_float2(sx, sy);
    } else {
      // low 16 bits = even d, high 16 = odd d (same packing as before)
      vTp[(size_t)d2 * BB + row] = (f2bf(sy) << 16) | f2bf(sx);
    }
  }

  __threadfence();        // device-scope release: cross-XCD visibility
  cg::this_grid().sync();

  // ---- Phase 2: block b computes logits row b and its LSE contribution ----
  const int b = blockIdx.x;
  const int c = t & 255;
  const int k = t >> 8;  // 0..1, D-dimension split
  __shared__ float us[DD];       // 2 KB: u row b
  __shared__ float ls[2][BB];    // 2 KB: k-partials
  __shared__ float lg[BB];       // 1 KB: logits row

  us[t] = u[(size_t)b * DD + t];
  __syncthreads();

  float al = 0.f, ah = 0.f;
  const unsigned* p = vTp + (size_t)(k * (D2 / 2)) * BB + c;
  const float* ub = us + k * (DD / 2);
#pragma unroll 8
  for (int i = 0; i < D2 / 2; ++i) {  // 128 dword loads, coalesced in c
    unsigned w = p[(size_t)i * BB];
    float vlo = __uint_as_float(w << 16);           // even d
    float vhi = __uint_as_float(w & 0xffff0000u);   // odd d
    al = fmaf(ub[2 * i],     vlo, al);  // LDS broadcast reads, conflict-free
    ah = fmaf(ub[2 * i + 1], vhi, ah);
  }
  ls[k][c] = al + ah;
  __syncthreads();

  if (t < BB) lg[t] = (ls[0][t] + ls[1][t]) * (1.f / (NN * NN));
  __syncthreads();

  if (t < 64) {  // wave 0: logsumexp over the 256 logits
    float x0 = lg[t], x1 = lg[t + 64], x2 = lg[t + 128], x3 = lg[t + 192];
    float m = fmaxf(fmaxf(x0, x1), fmaxf(x2, x3));
#pragma unroll
    for (int off = 32; off > 0; off >>= 1) m = fmaxf(m, __shfl_xor(m, off, 64));
    float e = __expf(x0 - m) + __expf(x1 - m) + __expf(x2 - m) + __expf(x3 - m);
#pragma unroll
    for (int off = 32; off > 0; off >>= 1) e += __shfl_xor(e, off, 64);
    if (t == 0) atomicAdd(out, -(lg[b] - (m + __logf(e))) * (1.f / BB));
  }
}

extern "C" void kernel_launch(void* const* d_in, const int* in_sizes, int n_in,
                              void* d_out, int out_size, void* d_ws, size_t ws_size,
                              hipStream_t stream) {
  // setup_inputs dict order: face_j first, ner_j second
  const float* face = (const float*)d_in[0];  // (B, N2, D)
  const float* ner  = (const float*)d_in[1];  // (B, N1, D)
  float* u = (float*)d_ws;                            // 512 KB fp32
  unsigned* vTp = (unsigned*)(u + (size_t)BB * DD);   // 256 KB packed bf16
  float* out = (float*)d_out;

  void* args[] = {(void*)&ner, (void*)&face, (void*)&u, (void*)&vTp, (void*)&out};
  hipLaunchCooperativeKernel(reinterpret_cast<void*>(fused_nce), dim3(BB),
                             dim3(512), args, 0, stream);
}

// Round 2
// 79.145 us; speedup vs baseline: 2.2052x; 2.2052x over previous
//
#include <hip/hip_runtime.h>
#include <hip/hip_bf16.h>

// Problem constants (B, N1, N2, D) = (256, 32, 32, 512)
#define BB 256
#define NN 32
#define DD 512
#define ROWS 2    // logits rows per block in row_lse_bf16
#define KSPLIT 4  // D-dimension split inside a block

static __device__ inline unsigned f2bf(float x) {
  union { float f; unsigned u; } a; a.f = x;
  unsigned r = a.u + 0x7fff + ((a.u >> 16) & 1);  // round-to-nearest-even
  return r >> 16;
}

// Kernel 1: u[b][d] = sum_n ner[b][n][d] (fp32);
//           vTp[d/2][c] = bf16x2(sum_f face[c][f][d], ... [d+1]) packed dword.
// One thread per float4 output group; blocks 0-127 ner, 128-255 face.
// Also zeroes out[0] (harness poisons 0xAA); stream order makes it visible to K2.
__global__ __launch_bounds__(256) void reduce_sums(
    const float* __restrict__ ner, const float* __restrict__ face,
    float* __restrict__ u, unsigned* __restrict__ vTp, float* __restrict__ out) {
  int idx = blockIdx.x * 256 + threadIdx.x;
  if (idx == 0) out[0] = 0.0f;
  const int half = BB * DD / 4;  // 32768 float4 outputs per tensor
  bool is_ner = idx < half;
  int j = is_ner ? idx : idx - half;
  int row = j >> 7;   // DD/4 = 128 float4 per row
  int d4  = j & 127;
  const float* src = is_ner ? ner : face;
  const float4* p = (const float4*)(src + (size_t)row * NN * DD) + d4;
  float4 s = make_float4(0.f, 0.f, 0.f, 0.f);
#pragma unroll
  for (int n = 0; n < NN; ++n) {
    float4 x = p[n * (DD / 4)];
    s.x += x.x; s.y += x.y; s.z += x.z; s.w += x.w;
  }
  if (is_ner) {
    ((float4*)(u + (size_t)row * DD))[d4] = s;
  } else {
    // d = 4*d4 .. 4*d4+3 ; dp = d>>1 ; low 16 bits = even d (unpacked as w<<16)
    int dp0 = 2 * d4;
    vTp[(size_t)dp0 * BB + row]       = (f2bf(s.y) << 16) | f2bf(s.x);
    vTp[(size_t)(dp0 + 1) * BB + row] = (f2bf(s.w) << 16) | f2bf(s.z);
  }
}

// Kernel 2: 128 blocks x 1024 threads. Block handles ROWS=2 logits rows.
// Thread (c = t&255, k = t>>8) accumulates a 128-d chunk of the dot for both
// rows; k-partials combined in LDS; wave w does row-w logsumexp via shuffles;
// one atomicAdd per block into out.
__global__ __launch_bounds__(1024) void row_lse_bf16(
    const float* __restrict__ u, const unsigned* __restrict__ vTp,
    float* __restrict__ out) {
  const int b0 = blockIdx.x * ROWS;
  const int t = threadIdx.x;
  const int c = t & 255;
  const int k = t >> 8;  // 0..3
  __shared__ float us[ROWS * DD];         // 4 KB (fp32 u rows)
  __shared__ float ls[KSPLIT][ROWS][BB];  // 8 KB (k-partials)
  __shared__ float lg[ROWS][BB];          // 2 KB (logits)
  __shared__ float wsum[ROWS];

  if (t < ROWS * DD / 4)  // 256 threads stage 2 rows of u as float4
    ((float4*)us)[t] = ((const float4*)(u + (size_t)b0 * DD))[t];
  __syncthreads();

  float a0l = 0.f, a0h = 0.f, a1l = 0.f, a1h = 0.f;
  const unsigned* p = vTp + (size_t)(k * (DD / 2 / KSPLIT)) * BB + c;
  const float* u0 = us + k * (DD / KSPLIT);
  const float* u1 = us + DD + k * (DD / KSPLIT);
#pragma unroll 8
  for (int i = 0; i < DD / 2 / KSPLIT; ++i) {  // 64 dword loads, coalesced in c
    unsigned w = p[(size_t)i * BB];
    float vlo = __uint_as_float(w << 16);          // even d
    float vhi = __uint_as_float(w & 0xffff0000u);  // odd d
    a0l = fmaf(u0[2 * i],     vlo, a0l);  // LDS broadcast reads, conflict-free
    a0h = fmaf(u0[2 * i + 1], vhi, a0h);
    a1l = fmaf(u1[2 * i],     vlo, a1l);
    a1h = fmaf(u1[2 * i + 1], vhi, a1h);
  }
  ls[k][0][c] = a0l + a0h;
  ls[k][1][c] = a1l + a1h;
  __syncthreads();

  const float sc = 1.f / (NN * NN);
  if (t < ROWS * BB) {  // combine k-partials: 512 threads, stride-1 in c
    int cc = t & 255, r = t >> 8;
    lg[r][cc] = (ls[0][r][cc] + ls[1][r][cc] + ls[2][r][cc] + ls[3][r][cc]) * sc;
  }
  __syncthreads();

  const int wv = t >> 6, lane = t & 63;
  if (wv < ROWS) {  // wave wv reduces row wv
    float x0 = lg[wv][lane];
    float x1 = lg[wv][lane + 64];
    float x2 = lg[wv][lane + 128];
    float x3 = lg[wv][lane + 192];
    float m = fmaxf(fmaxf(x0, x1), fmaxf(x2, x3));
#pragma unroll
    for (int off = 32; off > 0; off >>= 1) m = fmaxf(m, __shfl_xor(m, off, 64));
    float e = __expf(x0 - m) + __expf(x1 - m) + __expf(x2 - m) + __expf(x3 - m);
#pragma unroll
    for (int off = 32; off > 0; off >>= 1) e += __shfl_xor(e, off, 64);
    if (lane == 0) wsum[wv] = lg[wv][b0 + wv] - (m + __logf(e));
  }
  __syncthreads();
  if (t == 0) atomicAdd(out, -(wsum[0] + wsum[1]) * (1.f / BB));
}

extern "C" void kernel_launch(void* const* d_in, const int* in_sizes, int n_in,
                              void* d_out, int out_size, void* d_ws, size_t ws_size,
                              hipStream_t stream) {
  // setup_inputs dict order: face_j first, ner_j second
  const float* face = (const float*)d_in[0];  // (B, N2, D)
  const float* ner  = (const float*)d_in[1];  // (B, N1, D)
  float* u = (float*)d_ws;                       // 256*512 f32 = 512 KB
  unsigned* vTp = (unsigned*)(u + (size_t)BB * DD);  // 256*256 u32 = 256 KB
  float* out = (float*)d_out;

  const int total_threads = 2 * BB * DD / 4;  // 65536
  reduce_sums<<<total_threads / 256, 256, 0, stream>>>(ner, face, u, vTp, out);
  row_lse_bf16<<<BB / ROWS, 1024, 0, stream>>>(u, vTp, out);
}